// Round 1
// baseline (2304.433 us; speedup 1.0000x reference)
//
#include <hip/hip_runtime.h>
#include <hip/hip_bf16.h>

// ---------------------------------------------------------------------------
// GAT encoder: proj GEMM -> 3x (GEMM, per-dst segment softmax, CSR aggregate)
// Round 1: correctness-first. fp32 tiled GEMM (no MFMA yet), CSR-based
// attention (no atomics on hot path).
// ---------------------------------------------------------------------------

#define LB(x) __launch_bounds__(x)

// ---------------- CSR build ----------------
__global__ void k_deg(const int* __restrict__ ei, int E, int Np, int* __restrict__ deg) {
    int e = blockIdx.x * blockDim.x + threadIdx.x;
    if (e >= E + Np) return;
    int dst = (e < E) ? ei[E + e] : (e - E);
    atomicAdd(&deg[dst], 1);
}

__global__ LB(512) void k_scan(const int* __restrict__ deg, int* __restrict__ row_ptr,
                               int* __restrict__ cursor, int n) {
    __shared__ int sh[512];
    __shared__ int carry_sh;
    int t = threadIdx.x;
    if (t == 0) { carry_sh = 0; row_ptr[0] = 0; }
    __syncthreads();
    for (int base = 0; base < n; base += 512) {
        int i = base + t;
        int v = (i < n) ? deg[i] : 0;
        sh[t] = v;
        __syncthreads();
        for (int off = 1; off < 512; off <<= 1) {
            int add = (t >= off) ? sh[t - off] : 0;
            __syncthreads();
            sh[t] += add;
            __syncthreads();
        }
        int carry = carry_sh;
        if (i < n) {
            int inc = sh[t] + carry;
            row_ptr[i + 1] = inc;
            cursor[i] = inc - v;  // exclusive prefix
        }
        __syncthreads();
        if (t == 511) carry_sh = carry + sh[511];
        __syncthreads();
    }
}

__global__ void k_fill(const int* __restrict__ ei, int E, int Np,
                       int* __restrict__ cursor, int* __restrict__ col_src) {
    int e = blockIdx.x * blockDim.x + threadIdx.x;
    if (e >= E + Np) return;
    int src, dst;
    if (e < E) { src = ei[e]; dst = ei[E + e]; }
    else       { src = dst = e - E; }
    int pos = atomicAdd(&cursor[dst], 1);
    col_src[pos] = src;
}

// ---------------- GEMM: C = A[M,K] @ B[K,Nn] (+bias), fp32 ----------------
// BM=BN=128, BK=16, 256 threads, 8x8 per thread.
__global__ LB(256) void k_gemm(const float* __restrict__ A, const float* __restrict__ B,
                               const float* __restrict__ bias, float* __restrict__ C,
                               int M, int K, int Nn) {
    __shared__ float As[16][128];
    __shared__ float Bs[16][128];
    const int row0 = blockIdx.y * 128;
    const int col0 = blockIdx.x * 128;
    const int tid = threadIdx.x;
    const int tx = tid & 15;        // 0..15 (cols)
    const int ty = tid >> 4;        // 0..15 (rows)
    const int a_r = tid >> 2;       // 0..63
    const int a_k = (tid & 3) * 4;  // 0,4,8,12
    const int b_k = tid >> 5;       // 0..7
    const int b_c = (tid & 31) * 4; // 0..124

    float acc[8][8];
    #pragma unroll
    for (int i = 0; i < 8; ++i)
        #pragma unroll
        for (int j = 0; j < 8; ++j) acc[i][j] = 0.f;

    for (int k0 = 0; k0 < K; k0 += 16) {
        #pragma unroll
        for (int i = 0; i < 2; ++i) {
            int r = row0 + a_r + i * 64;
            float4 v = make_float4(0.f, 0.f, 0.f, 0.f);
            if (r < M) v = *(const float4*)&A[(size_t)r * K + k0 + a_k];
            As[a_k + 0][a_r + i * 64] = v.x;
            As[a_k + 1][a_r + i * 64] = v.y;
            As[a_k + 2][a_r + i * 64] = v.z;
            As[a_k + 3][a_r + i * 64] = v.w;
        }
        #pragma unroll
        for (int i = 0; i < 2; ++i) {
            int kk = b_k + i * 8;
            *(float4*)&Bs[kk][b_c] = *(const float4*)&B[(size_t)(k0 + kk) * Nn + col0 + b_c];
        }
        __syncthreads();
        #pragma unroll
        for (int kk = 0; kk < 16; ++kk) {
            float a[8], b[8];
            *(float4*)&a[0] = *(const float4*)&As[kk][ty * 8];
            *(float4*)&a[4] = *(const float4*)&As[kk][ty * 8 + 4];
            *(float4*)&b[0] = *(const float4*)&Bs[kk][tx * 8];
            *(float4*)&b[4] = *(const float4*)&Bs[kk][tx * 8 + 4];
            #pragma unroll
            for (int i = 0; i < 8; ++i)
                #pragma unroll
                for (int j = 0; j < 8; ++j)
                    acc[i][j] = fmaf(a[i], b[j], acc[i][j]);
        }
        __syncthreads();
    }

    #pragma unroll
    for (int i = 0; i < 8; ++i) {
        int r = row0 + ty * 8 + i;
        if (r >= M) break;
        #pragma unroll
        for (int j4 = 0; j4 < 2; ++j4) {
            int c = col0 + tx * 8 + j4 * 4;
            float4 v;
            v.x = acc[i][j4 * 4 + 0] + (bias ? bias[c + 0] : 0.f);
            v.y = acc[i][j4 * 4 + 1] + (bias ? bias[c + 1] : 0.f);
            v.z = acc[i][j4 * 4 + 2] + (bias ? bias[c + 2] : 0.f);
            v.w = acc[i][j4 * 4 + 3] + (bias ? bias[c + 3] : 0.f);
            *(float4*)&C[(size_t)r * Nn + c] = v;
        }
    }
}

// ---------------- attention scalars: a_src/a_dst[n,h] = <h[n,h,:], att> ----
// grid = N, block = 64*H (one wave per head)
__global__ void k_att(const float* __restrict__ hW, const float* __restrict__ att_s,
                      const float* __restrict__ att_d, float* __restrict__ a_src,
                      float* __restrict__ a_dst, int H, int C) {
    int n = blockIdx.x;
    int w = threadIdx.x >> 6;   // head
    int lane = threadIdx.x & 63;
    const float* hp = hW + (size_t)n * H * C + (size_t)w * C;
    float s1 = 0.f, s2 = 0.f;
    for (int i = lane; i < C; i += 64) {
        float hv = hp[i];
        s1 += hv * att_s[w * C + i];
        s2 += hv * att_d[w * C + i];
    }
    #pragma unroll
    for (int off = 32; off; off >>= 1) {
        s1 += __shfl_xor(s1, off);
        s2 += __shfl_xor(s2, off);
    }
    if (lane == 0) { a_src[n * H + w] = s1; a_dst[n * H + w] = s2; }
}

// ---------------- segment softmax over incoming edges, per dst ----------
// grid = N, block = 64 (one wave). alpha written in CSR edge order.
__global__ LB(64) void k_softmax(const int* __restrict__ row_ptr, const int* __restrict__ col_src,
                                 const float* __restrict__ a_src, const float* __restrict__ a_dst,
                                 float* __restrict__ alpha, int H) {
    int d = blockIdx.x;
    int t = threadIdx.x;
    int s = row_ptr[d], eend = row_ptr[d + 1];
    for (int h = 0; h < H; ++h) {
        float adh = a_dst[d * H + h];
        float m = -1e30f;
        for (int e = s + t; e < eend; e += 64) {
            float v = a_src[col_src[e] * H + h] + adh;
            v = (v > 0.f) ? v : 0.2f * v;
            m = fmaxf(m, v);
        }
        #pragma unroll
        for (int off = 32; off; off >>= 1) m = fmaxf(m, __shfl_xor(m, off));
        float sum = 0.f;
        for (int e = s + t; e < eend; e += 64) {
            float v = a_src[col_src[e] * H + h] + adh;
            v = (v > 0.f) ? v : 0.2f * v;
            sum += __expf(v - m);
        }
        #pragma unroll
        for (int off = 32; off; off >>= 1) sum += __shfl_xor(sum, off);
        float inv = 1.0f / sum;
        for (int e = s + t; e < eend; e += 64) {
            float v = a_src[col_src[e] * H + h] + adh;
            v = (v > 0.f) ? v : 0.2f * v;
            alpha[e * H + h] = __expf(v - m) * inv;
        }
    }
}

// ---------------- aggregate: out[d,:] = sum_e alpha[e,h] * hW[src,:] + bias
// grid = N, block = 256 (F=2048) or 128 (F=512). elu applied if flag.
__global__ LB(256) void k_agg(const int* __restrict__ row_ptr, const int* __restrict__ col_src,
                              const float* __restrict__ alpha, const float* __restrict__ hW,
                              const float* __restrict__ bias, float* __restrict__ out,
                              int H, int C, int elu) {
    int d = blockIdx.x;
    int tid = threadIdx.x;
    int F4 = (H * C) >> 2;            // float4 count: 512 or 128
    int idx0 = tid;
    int idx1 = tid + 256;
    bool has0 = idx0 < F4;
    bool has1 = idx1 < F4;
    int h0 = (idx0 * 4) / C;
    int h1 = (idx1 * 4) / C;
    float4 acc0 = make_float4(0.f, 0.f, 0.f, 0.f);
    float4 acc1 = make_float4(0.f, 0.f, 0.f, 0.f);
    const float4* hw4 = (const float4*)hW;
    int s = row_ptr[d], eend = row_ptr[d + 1];
    for (int e = s; e < eend; ++e) {
        int src = col_src[e];
        const float4* hp = hw4 + (size_t)src * F4;
        if (has0) {
            float a = alpha[e * H + h0];
            float4 v = hp[idx0];
            acc0.x = fmaf(a, v.x, acc0.x); acc0.y = fmaf(a, v.y, acc0.y);
            acc0.z = fmaf(a, v.z, acc0.z); acc0.w = fmaf(a, v.w, acc0.w);
        }
        if (has1) {
            float a = alpha[e * H + h1];
            float4 v = hp[idx1];
            acc1.x = fmaf(a, v.x, acc1.x); acc1.y = fmaf(a, v.y, acc1.y);
            acc1.z = fmaf(a, v.z, acc1.z); acc1.w = fmaf(a, v.w, acc1.w);
        }
    }
    if (has0) {
        const float4 b4 = *(const float4*)&bias[idx0 * 4];
        float4 r;
        r.x = acc0.x + b4.x; r.y = acc0.y + b4.y; r.z = acc0.z + b4.z; r.w = acc0.w + b4.w;
        if (elu) {
            r.x = (r.x > 0.f) ? r.x : __expf(r.x) - 1.f;
            r.y = (r.y > 0.f) ? r.y : __expf(r.y) - 1.f;
            r.z = (r.z > 0.f) ? r.z : __expf(r.z) - 1.f;
            r.w = (r.w > 0.f) ? r.w : __expf(r.w) - 1.f;
        }
        *(float4*)&out[(size_t)d * F4 * 4 + idx0 * 4] = r;
    }
    if (has1) {
        const float4 b4 = *(const float4*)&bias[idx1 * 4];
        float4 r;
        r.x = acc1.x + b4.x; r.y = acc1.y + b4.y; r.z = acc1.z + b4.z; r.w = acc1.w + b4.w;
        if (elu) {
            r.x = (r.x > 0.f) ? r.x : __expf(r.x) - 1.f;
            r.y = (r.y > 0.f) ? r.y : __expf(r.y) - 1.f;
            r.z = (r.z > 0.f) ? r.z : __expf(r.z) - 1.f;
            r.w = (r.w > 0.f) ? r.w : __expf(r.w) - 1.f;
        }
        *(float4*)&out[(size_t)d * F4 * 4 + idx1 * 4] = r;
    }
}

// ---------------------------------------------------------------------------
extern "C" void kernel_launch(void* const* d_in, const int* in_sizes, int n_in,
                              void* d_out, int out_size, void* d_ws, size_t ws_size,
                              hipStream_t stream) {
    const float* x      = (const float*)d_in[0];
    const int*   ei     = (const int*)d_in[1];
    const float* proj_W = (const float*)d_in[2];
    const float* proj_b = (const float*)d_in[3];
    const float* W1  = (const float*)d_in[4];
    const float* as1 = (const float*)d_in[5];
    const float* ad1 = (const float*)d_in[6];
    const float* b1  = (const float*)d_in[7];
    const float* W2  = (const float*)d_in[8];
    const float* as2 = (const float*)d_in[9];
    const float* ad2 = (const float*)d_in[10];
    const float* b2  = (const float*)d_in[11];
    const float* W3  = (const float*)d_in[12];
    const float* as3 = (const float*)d_in[13];
    const float* ad3 = (const float*)d_in[14];
    const float* b3  = (const float*)d_in[15];
    float* out = (float*)d_out;

    const int N  = in_sizes[0] / 256;   // 10000
    const int E  = in_sizes[1] / 2;     // 160000
    const int Ep = E + N;               // with self-loops

    // workspace carve-up (~168 MB)
    size_t off = 0;
    auto alloc = [&](size_t bytes) -> void* {
        void* p = (char*)d_ws + off;
        off += (bytes + 255) & ~(size_t)255;
        return p;
    };
    float* buf0    = (float*)alloc((size_t)N * 2048 * 4);
    float* buf1    = (float*)alloc((size_t)N * 2048 * 4);
    float* a_src   = (float*)alloc((size_t)N * 4 * 4);
    float* a_dst   = (float*)alloc((size_t)N * 4 * 4);
    float* alpha   = (float*)alloc((size_t)Ep * 4 * 4);
    int*   deg     = (int*)alloc((size_t)N * 4);
    int*   cursor  = (int*)alloc((size_t)N * 4);
    int*   row_ptr = (int*)alloc((size_t)(N + 1) * 4);
    int*   col_src = (int*)alloc((size_t)Ep * 4);
    (void)ws_size;

    // ---- CSR build (per call; deterministic work) ----
    hipMemsetAsync(deg, 0, (size_t)N * 4, stream);
    int eb = (Ep + 255) / 256;
    k_deg<<<eb, 256, 0, stream>>>(ei, E, N, deg);
    k_scan<<<1, 512, 0, stream>>>(deg, row_ptr, cursor, N);
    k_fill<<<eb, 256, 0, stream>>>(ei, E, N, cursor, col_src);

    const int MB = (N + 127) / 128;  // 79

    // ---- proj: h0 = x @ proj_W + proj_b  [N,512] -> buf0 ----
    k_gemm<<<dim3(512 / 128, MB), 256, 0, stream>>>(x, proj_W, proj_b, buf0, N, 256, 512);

    // ---- layer 1 (H=4, C=512, concat, ELU) ----
    k_gemm<<<dim3(2048 / 128, MB), 256, 0, stream>>>(buf0, W1, nullptr, buf1, N, 512, 2048);
    k_att<<<N, 256, 0, stream>>>(buf1, as1, ad1, a_src, a_dst, 4, 512);
    k_softmax<<<N, 64, 0, stream>>>(row_ptr, col_src, a_src, a_dst, alpha, 4);
    k_agg<<<N, 256, 0, stream>>>(row_ptr, col_src, alpha, buf1, b1, buf0, 4, 512, 1);

    // ---- layer 2 (H=4, C=512, concat, ELU) ----
    k_gemm<<<dim3(2048 / 128, MB), 256, 0, stream>>>(buf0, W2, nullptr, buf1, N, 2048, 2048);
    k_att<<<N, 256, 0, stream>>>(buf1, as2, ad2, a_src, a_dst, 4, 512);
    k_softmax<<<N, 64, 0, stream>>>(row_ptr, col_src, a_src, a_dst, alpha, 4);
    k_agg<<<N, 256, 0, stream>>>(row_ptr, col_src, alpha, buf1, b2, buf0, 4, 512, 1);

    // ---- layer 3 (H=1, C=512, mean over 1 head = identity, no ELU) ----
    k_gemm<<<dim3(512 / 128, MB), 256, 0, stream>>>(buf0, W3, nullptr, buf1, N, 2048, 512);
    k_att<<<N, 64, 0, stream>>>(buf1, as3, ad3, a_src, a_dst, 1, 512);
    k_softmax<<<N, 64, 0, stream>>>(row_ptr, col_src, a_src, a_dst, alpha, 1);
    k_agg<<<N, 128, 0, stream>>>(row_ptr, col_src, alpha, buf1, b3, out, 1, 512, 0);
}

// Round 3
// 1157.114 us; speedup vs baseline: 1.9915x; 1.9915x over previous
//
#include <hip/hip_runtime.h>
#include <hip/hip_bf16.h>

// ---------------------------------------------------------------------------
// GAT encoder, round 3: emulated-fp32 GEMM via hi/lo split bf16 MFMA
// (3 products: Ahi*Bhi + Ahi*Blo + Alo*Bhi, fp32 accum -> ~2^-17 relative).
// All activations stored packed u32 {bf16 hi, bf16 lo}. Attention/softmax/
// aggregate reconstruct exact fp32. CSR attention, no atomics on hot path.
// Weights JIT-transposed+packed into d_out scratch (overwritten by final agg).
// ---------------------------------------------------------------------------

#define LB(x) __launch_bounds__(x)

typedef unsigned short u16;
typedef unsigned int u32;
typedef __attribute__((ext_vector_type(8))) short bf16x8;
typedef __attribute__((ext_vector_type(4))) float f32x4;

__device__ __forceinline__ float b2f(u16 u) {
    union { float f; u32 u; } x;
    x.u = ((u32)u) << 16;
    return x.f;
}
__device__ __forceinline__ u16 f2b(float f) {
    u32 u = __float_as_uint(f);
    u = (u + 0x7FFFu + ((u >> 16) & 1u)) >> 16;   // RNE
    return (u16)u;
}
// pack v as {hi, lo}: hi = bf16(v), lo = bf16(v - hi)
__device__ __forceinline__ u32 pack2(float v) {
    u16 hi = f2b(v);
    u16 lo = f2b(v - b2f(hi));
    return ((u32)hi << 16) | (u32)lo;
}
__device__ __forceinline__ float rec2(u32 p) {
    return b2f((u16)(p >> 16)) + b2f((u16)p);
}
__device__ __forceinline__ void lds_cp16u(const u32* g, u32* l) {
    __builtin_amdgcn_global_load_lds(
        (const __attribute__((address_space(1))) unsigned int*)g,
        (__attribute__((address_space(3))) unsigned int*)l, 16, 0, 0);
}

// ---------------- CSR build ----------------
__global__ void k_deg(const int* __restrict__ ei, int E, int Np, int* __restrict__ deg) {
    int e = blockIdx.x * blockDim.x + threadIdx.x;
    if (e >= E + Np) return;
    int dst = (e < E) ? ei[E + e] : (e - E);
    atomicAdd(&deg[dst], 1);
}

__global__ LB(512) void k_scan(const int* __restrict__ deg, int* __restrict__ row_ptr,
                               int* __restrict__ cursor, int n) {
    __shared__ int sh[512];
    __shared__ int carry_sh;
    int t = threadIdx.x;
    if (t == 0) { carry_sh = 0; row_ptr[0] = 0; }
    __syncthreads();
    for (int base = 0; base < n; base += 512) {
        int i = base + t;
        int v = (i < n) ? deg[i] : 0;
        sh[t] = v;
        __syncthreads();
        for (int off = 1; off < 512; off <<= 1) {
            int add = (t >= off) ? sh[t - off] : 0;
            __syncthreads();
            sh[t] += add;
            __syncthreads();
        }
        int carry = carry_sh;
        if (i < n) {
            int inc = sh[t] + carry;
            row_ptr[i + 1] = inc;
            cursor[i] = inc - v;
        }
        __syncthreads();
        if (t == 511) carry_sh = carry + sh[511];
        __syncthreads();
    }
}

__global__ void k_fill(const int* __restrict__ ei, int E, int Np,
                       int* __restrict__ cursor, int* __restrict__ col_src) {
    int e = blockIdx.x * blockDim.x + threadIdx.x;
    if (e >= E + Np) return;
    int src, dst;
    if (e < E) { src = ei[e]; dst = ei[E + e]; }
    else       { src = dst = e - E; }
    int pos = atomicAdd(&cursor[dst], 1);
    col_src[pos] = src;
}

// ---------------- fp32 -> packed hi/lo ----------------
__global__ void k_pack(const float* __restrict__ in, u32* __restrict__ out, int n4) {
    int i = blockIdx.x * blockDim.x + threadIdx.x;
    if (i >= n4) return;
    float4 v = ((const float4*)in)[i];
    uint4 o;
    o.x = pack2(v.x); o.y = pack2(v.y); o.z = pack2(v.z); o.w = pack2(v.w);
    ((uint4*)out)[i] = o;
}

// ---------------- weight transpose + pack: Wt[n][k] = split(W[k][n]) -------
__global__ LB(256) void k_wt_pack(const float* __restrict__ W, u32* __restrict__ Wt,
                                  int K, int Nn) {
    __shared__ float sh[32][33];
    int n0 = blockIdx.x * 32, k0 = blockIdx.y * 32;
    int c = threadIdx.x & 31, r0 = threadIdx.x >> 5;
    #pragma unroll
    for (int r = r0; r < 32; r += 8)
        sh[r][c] = W[(size_t)(k0 + r) * Nn + n0 + c];
    __syncthreads();
    #pragma unroll
    for (int r = r0; r < 32; r += 8)
        Wt[(size_t)(n0 + r) * K + k0 + c] = pack2(sh[c][r]);
}

// ---------------- split-bf16 MFMA GEMM: C = A[M,K] @ Bt[Nn,K]^T ------------
// packed u32 inputs/outputs; 128x128 tile, BK=32, 4 waves (2x2), 64x64/wave.
__global__ LB(256) void k_gemm_pk(const u32* __restrict__ A, const u32* __restrict__ Bt,
                                  const float* __restrict__ bias, u32* __restrict__ C,
                                  int M, int K, int Nn) {
    __shared__ u32 As[128 * 32];
    __shared__ u32 Bs[128 * 32];
    const int tid  = threadIdx.x;
    const int lane = tid & 63;
    const int w    = tid >> 6;
    const int wr   = w >> 1;
    const int wc   = w & 1;
    const int row0 = blockIdx.y * 128;
    const int col0 = blockIdx.x * 128;
    const int ln15 = lane & 15;
    const int lq   = lane >> 4;

    f32x4 acc[4][4];
    #pragma unroll
    for (int m = 0; m < 4; ++m)
        #pragma unroll
        for (int n = 0; n < 4; ++n) acc[m][n] = (f32x4){0.f, 0.f, 0.f, 0.f};

    for (int k0 = 0; k0 < K; k0 += 32) {
        // stage 128x32 u32 tiles (16 KB each): 1024 16B-chunks, 4 per thread.
        #pragma unroll
        for (int i = 0; i < 4; ++i) {
            int c = i * 256 + tid;
            int row = c >> 3, kc = (c & 7) * 4;
            int gr = row0 + row; if (gr >= M) gr = M - 1;   // tail clamp
            lds_cp16u(A  + (size_t)gr * K + k0 + kc, &As[c * 4]);
            lds_cp16u(Bt + (size_t)(col0 + row) * K + k0 + kc, &Bs[c * 4]);
        }
        __syncthreads();
        bf16x8 ah[4], al[4], bh[4], bl[4];
        #pragma unroll
        for (int m = 0; m < 4; ++m) {
            const u32* p = &As[(wr * 64 + m * 16 + ln15) * 32 + lq * 8];
            uint4 q0 = *(const uint4*)p;
            uint4 q1 = *(const uint4*)(p + 4);
            ah[m][0] = (short)(q0.x >> 16); al[m][0] = (short)q0.x;
            ah[m][1] = (short)(q0.y >> 16); al[m][1] = (short)q0.y;
            ah[m][2] = (short)(q0.z >> 16); al[m][2] = (short)q0.z;
            ah[m][3] = (short)(q0.w >> 16); al[m][3] = (short)q0.w;
            ah[m][4] = (short)(q1.x >> 16); al[m][4] = (short)q1.x;
            ah[m][5] = (short)(q1.y >> 16); al[m][5] = (short)q1.y;
            ah[m][6] = (short)(q1.z >> 16); al[m][6] = (short)q1.z;
            ah[m][7] = (short)(q1.w >> 16); al[m][7] = (short)q1.w;
        }
        #pragma unroll
        for (int n = 0; n < 4; ++n) {
            const u32* p = &Bs[(wc * 64 + n * 16 + ln15) * 32 + lq * 8];
            uint4 q0 = *(const uint4*)p;
            uint4 q1 = *(const uint4*)(p + 4);
            bh[n][0] = (short)(q0.x >> 16); bl[n][0] = (short)q0.x;
            bh[n][1] = (short)(q0.y >> 16); bl[n][1] = (short)q0.y;
            bh[n][2] = (short)(q0.z >> 16); bl[n][2] = (short)q0.z;
            bh[n][3] = (short)(q0.w >> 16); bl[n][3] = (short)q0.w;
            bh[n][4] = (short)(q1.x >> 16); bl[n][4] = (short)q1.x;
            bh[n][5] = (short)(q1.y >> 16); bl[n][5] = (short)q1.y;
            bh[n][6] = (short)(q1.z >> 16); bl[n][6] = (short)q1.z;
            bh[n][7] = (short)(q1.w >> 16); bl[n][7] = (short)q1.w;
        }
        #pragma unroll
        for (int m = 0; m < 4; ++m)
            #pragma unroll
            for (int n = 0; n < 4; ++n) {
                acc[m][n] = __builtin_amdgcn_mfma_f32_16x16x32_bf16(al[m], bh[n], acc[m][n], 0, 0, 0);
                acc[m][n] = __builtin_amdgcn_mfma_f32_16x16x32_bf16(ah[m], bl[n], acc[m][n], 0, 0, 0);
                acc[m][n] = __builtin_amdgcn_mfma_f32_16x16x32_bf16(ah[m], bh[n], acc[m][n], 0, 0, 0);
            }
        __syncthreads();
    }

    // D: col = lane&15, row = (lane>>4)*4 + j  [m89/m91-verified]
    #pragma unroll
    for (int m = 0; m < 4; ++m) {
        #pragma unroll
        for (int n = 0; n < 4; ++n) {
            int gc = col0 + wc * 64 + n * 16 + ln15;
            float badd = bias ? bias[gc] : 0.f;
            #pragma unroll
            for (int j = 0; j < 4; ++j) {
                int gr = row0 + wr * 64 + m * 16 + lq * 4 + j;
                if (gr < M) C[(size_t)gr * Nn + gc] = pack2(acc[m][n][j] + badd);
            }
        }
    }
}

// ---------------- attention scalars from packed h ----------------
// grid = N, block = 64*H; C == 512.
__global__ void k_att(const u32* __restrict__ h_pk, const float* __restrict__ att_s,
                      const float* __restrict__ att_d, float* __restrict__ a_src,
                      float* __restrict__ a_dst, int H, int C) {
    int n = blockIdx.x;
    int w = threadIdx.x >> 6;
    int lane = threadIdx.x & 63;
    int o = lane * 8;
    const u32* hp = h_pk + (size_t)n * H * C + (size_t)w * C + o;
    uint4 p0 = ((const uint4*)hp)[0];
    uint4 p1 = ((const uint4*)hp)[1];
    float hv[8] = { rec2(p0.x), rec2(p0.y), rec2(p0.z), rec2(p0.w),
                    rec2(p1.x), rec2(p1.y), rec2(p1.z), rec2(p1.w) };
    float s1 = 0.f, s2 = 0.f;
    #pragma unroll
    for (int j = 0; j < 8; ++j) {
        s1 = fmaf(hv[j], att_s[w * C + o + j], s1);
        s2 = fmaf(hv[j], att_d[w * C + o + j], s2);
    }
    #pragma unroll
    for (int off = 32; off; off >>= 1) {
        s1 += __shfl_xor(s1, off);
        s2 += __shfl_xor(s2, off);
    }
    if (lane == 0) { a_src[n * H + w] = s1; a_dst[n * H + w] = s2; }
}

// ---------------- segment softmax per dst (one wave) ----------------
__global__ LB(64) void k_softmax(const int* __restrict__ row_ptr, const int* __restrict__ col_src,
                                 const float* __restrict__ a_src, const float* __restrict__ a_dst,
                                 float* __restrict__ alpha, int H) {
    int d = blockIdx.x;
    int t = threadIdx.x;
    int s = row_ptr[d], eend = row_ptr[d + 1];
    for (int h = 0; h < H; ++h) {
        float adh = a_dst[d * H + h];
        float m = -1e30f;
        for (int e = s + t; e < eend; e += 64) {
            float v = a_src[col_src[e] * H + h] + adh;
            v = (v > 0.f) ? v : 0.2f * v;
            m = fmaxf(m, v);
        }
        #pragma unroll
        for (int off = 32; off; off >>= 1) m = fmaxf(m, __shfl_xor(m, off));
        float sum = 0.f;
        for (int e = s + t; e < eend; e += 64) {
            float v = a_src[col_src[e] * H + h] + adh;
            v = (v > 0.f) ? v : 0.2f * v;
            sum += __expf(v - m);
        }
        #pragma unroll
        for (int off = 32; off; off >>= 1) sum += __shfl_xor(sum, off);
        float inv = 1.0f / sum;
        for (int e = s + t; e < eend; e += 64) {
            float v = a_src[col_src[e] * H + h] + adh;
            v = (v > 0.f) ? v : 0.2f * v;
            alpha[e * H + h] = __expf(v - m) * inv;
        }
    }
}

// ---------------- aggregate: out[d] = sum_e alpha[e,h]*h[src] (+bias,ELU) --
// block = F/8 threads; each thread owns 8 contiguous elements.
template <bool PACK_OUT, bool ELU_>
__global__ LB(256) void k_agg(const int* __restrict__ row_ptr, const int* __restrict__ col_src,
                              const float* __restrict__ alpha, const u32* __restrict__ h_pk,
                              const float* __restrict__ bias, void* __restrict__ out,
                              int H, int C) {
    int d = blockIdx.x;
    int tid = threadIdx.x;
    int F = H * C;
    int o = tid * 8;
    int h0 = o / C;   // wave-uniform for C=512
    float acc[8];
    #pragma unroll
    for (int j = 0; j < 8; ++j) acc[j] = 0.f;
    int s = row_ptr[d], eend = row_ptr[d + 1];
    for (int e = s; e < eend; ++e) {
        int src = col_src[e];
        float a = alpha[e * H + h0];
        const uint4* hp = (const uint4*)(h_pk + (size_t)src * F + o);
        uint4 p0 = hp[0], p1 = hp[1];
        acc[0] = fmaf(a, rec2(p0.x), acc[0]);
        acc[1] = fmaf(a, rec2(p0.y), acc[1]);
        acc[2] = fmaf(a, rec2(p0.z), acc[2]);
        acc[3] = fmaf(a, rec2(p0.w), acc[3]);
        acc[4] = fmaf(a, rec2(p1.x), acc[4]);
        acc[5] = fmaf(a, rec2(p1.y), acc[5]);
        acc[6] = fmaf(a, rec2(p1.z), acc[6]);
        acc[7] = fmaf(a, rec2(p1.w), acc[7]);
    }
    #pragma unroll
    for (int j = 0; j < 8; ++j) {
        acc[j] += bias[o + j];
        if (ELU_) acc[j] = (acc[j] > 0.f) ? acc[j] : __expf(acc[j]) - 1.f;
    }
    if (PACK_OUT) {
        uint4 r0, r1;
        r0.x = pack2(acc[0]); r0.y = pack2(acc[1]); r0.z = pack2(acc[2]); r0.w = pack2(acc[3]);
        r1.x = pack2(acc[4]); r1.y = pack2(acc[5]); r1.z = pack2(acc[6]); r1.w = pack2(acc[7]);
        uint4* po = (uint4*)((u32*)out + (size_t)d * F + o);
        po[0] = r0; po[1] = r1;
    } else {
        float* po = (float*)out + (size_t)d * F + o;
        #pragma unroll
        for (int j4 = 0; j4 < 2; ++j4) {
            float4 r;
            r.x = acc[j4 * 4 + 0]; r.y = acc[j4 * 4 + 1];
            r.z = acc[j4 * 4 + 2]; r.w = acc[j4 * 4 + 3];
            *(float4*)&po[j4 * 4] = r;
        }
    }
}

// ---------------------------------------------------------------------------
extern "C" void kernel_launch(void* const* d_in, const int* in_sizes, int n_in,
                              void* d_out, int out_size, void* d_ws, size_t ws_size,
                              hipStream_t stream) {
    const float* x      = (const float*)d_in[0];
    const int*   ei     = (const int*)d_in[1];
    const float* proj_W = (const float*)d_in[2];
    const float* proj_b = (const float*)d_in[3];
    const float* W1  = (const float*)d_in[4];
    const float* as1 = (const float*)d_in[5];
    const float* ad1 = (const float*)d_in[6];
    const float* b1  = (const float*)d_in[7];
    const float* W2  = (const float*)d_in[8];
    const float* as2 = (const float*)d_in[9];
    const float* ad2 = (const float*)d_in[10];
    const float* b2  = (const float*)d_in[11];
    const float* W3  = (const float*)d_in[12];
    const float* as3 = (const float*)d_in[13];
    const float* ad3 = (const float*)d_in[14];
    const float* b3  = (const float*)d_in[15];

    const int N  = in_sizes[0] / 256;   // 10000
    const int E  = in_sizes[1] / 2;     // 160000
    const int Ep = E + N;

    // workspace carve-up (matches round-1's proven 167.7 MB footprint)
    size_t off = 0;
    auto alloc = [&](size_t bytes) -> void* {
        void* p = (char*)d_ws + off;
        off += (bytes + 255) & ~(size_t)255;
        return p;
    };
    u32* bufA = (u32*)alloc((size_t)N * 2048 * 4);   // packed acts / GEMM out
    u32* bufB = (u32*)alloc((size_t)N * 2048 * 4);   // packed acts / GEMM out
    float* a_src   = (float*)alloc((size_t)N * 4 * 4);
    float* a_dst   = (float*)alloc((size_t)N * 4 * 4);
    float* alpha   = (float*)alloc((size_t)Ep * 4 * 4);
    int*   deg     = (int*)alloc((size_t)N * 4);
    int*   cursor  = (int*)alloc((size_t)N * 4);
    int*   row_ptr = (int*)alloc((size_t)(N + 1) * 4);
    int*   col_src = (int*)alloc((size_t)Ep * 4);
    (void)ws_size;

    // JIT-packed transposed weights live in d_out (16.78 MB <= 20.48 MB);
    // the final aggregate overwrites all of d_out afterwards.
    u32* wpk = (u32*)d_out;

    // ---- CSR build ----
    hipMemsetAsync(deg, 0, (size_t)N * 4, stream);
    int eb = (Ep + 255) / 256;
    k_deg<<<eb, 256, 0, stream>>>(ei, E, N, deg);
    k_scan<<<1, 512, 0, stream>>>(deg, row_ptr, cursor, N);
    k_fill<<<eb, 256, 0, stream>>>(ei, E, N, cursor, col_src);

    const int MB = (N + 127) / 128;  // 79

    // ---- pack x into bufB[:, :256] ----
    k_pack<<<(N * 256 / 4 + 255) / 256, 256, 0, stream>>>(x, bufB, N * 256 / 4);

    // ---- proj: bufA = x @ proj_W + proj_b  [N,512] ----
    k_wt_pack<<<dim3(512 / 32, 256 / 32), 256, 0, stream>>>(proj_W, wpk, 256, 512);
    k_gemm_pk<<<dim3(512 / 128, MB), 256, 0, stream>>>(bufB, wpk, proj_b, bufA, N, 256, 512);

    // ---- layer 1 (H=4, C=512, concat, ELU) ----
    k_wt_pack<<<dim3(2048 / 32, 512 / 32), 256, 0, stream>>>(W1, wpk, 512, 2048);
    k_gemm_pk<<<dim3(2048 / 128, MB), 256, 0, stream>>>(bufA, wpk, nullptr, bufB, N, 512, 2048);
    k_att<<<N, 256, 0, stream>>>(bufB, as1, ad1, a_src, a_dst, 4, 512);
    k_softmax<<<N, 64, 0, stream>>>(row_ptr, col_src, a_src, a_dst, alpha, 4);
    k_agg<true, true><<<N, 256, 0, stream>>>(row_ptr, col_src, alpha, bufB, b1, bufA, 4, 512);

    // ---- layer 2 (H=4, C=512, concat, ELU) ----
    k_wt_pack<<<dim3(2048 / 32, 2048 / 32), 256, 0, stream>>>(W2, wpk, 2048, 2048);
    k_gemm_pk<<<dim3(2048 / 128, MB), 256, 0, stream>>>(bufA, wpk, nullptr, bufB, N, 2048, 2048);
    k_att<<<N, 256, 0, stream>>>(bufB, as2, ad2, a_src, a_dst, 4, 512);
    k_softmax<<<N, 64, 0, stream>>>(row_ptr, col_src, a_src, a_dst, alpha, 4);
    k_agg<true, true><<<N, 256, 0, stream>>>(row_ptr, col_src, alpha, bufB, b2, bufA, 4, 512);

    // ---- layer 3 (H=1, C=512, mean over single head = identity, no ELU) ----
    k_wt_pack<<<dim3(512 / 32, 2048 / 32), 256, 0, stream>>>(W3, wpk, 2048, 512);
    k_gemm_pk<<<dim3(512 / 128, MB), 256, 0, stream>>>(bufA, wpk, nullptr, bufB, N, 2048, 512);
    k_att<<<N, 64, 0, stream>>>(bufB, as3, ad3, a_src, a_dst, 1, 512);
    k_softmax<<<N, 64, 0, stream>>>(row_ptr, col_src, a_src, a_dst, alpha, 1);
    k_agg<false, false><<<N, 64, 0, stream>>>(row_ptr, col_src, alpha, bufB, b3, d_out, 1, 512);
}

// Round 4
// 1119.417 us; speedup vs baseline: 2.0586x; 1.0337x over previous
//
#include <hip/hip_runtime.h>
#include <hip/hip_bf16.h>

// ---------------------------------------------------------------------------
// GAT encoder, round 4: emulated-fp32 GEMM via hi/lo split bf16 MFMA
// (3 products: Ahi*Bhi + Ahi*Blo + Alo*Bhi, fp32 accum -> ~2^-17 relative).
// Round-4 change: hi/lo stored as SEPARATE bf16 planes (no packed-u32 unpack
// VALU in the GEMM), and LDS tiles use XOR swizzle (row&7)<<4 with
// inverse-swizzled global_load_lds source -> 16-way bank conflict -> 2-way.
// CSR attention, no atomics on hot path. Weight planes JIT-built in d_out.
// ---------------------------------------------------------------------------

#define LB(x) __launch_bounds__(x)

typedef unsigned short u16;
typedef unsigned int u32;
typedef __attribute__((ext_vector_type(8))) short bf16x8;
typedef __attribute__((ext_vector_type(4))) float f32x4;

__device__ __forceinline__ float b2f(u16 u) {
    union { float f; u32 u; } x;
    x.u = ((u32)u) << 16;
    return x.f;
}
__device__ __forceinline__ u16 f2b(float f) {
    u32 u = __float_as_uint(f);
    u = (u + 0x7FFFu + ((u >> 16) & 1u)) >> 16;   // RNE
    return (u16)u;
}
__device__ __forceinline__ void lds_cp16(const void* g, void* l) {
    __builtin_amdgcn_global_load_lds(
        (const __attribute__((address_space(1))) unsigned int*)g,
        (__attribute__((address_space(3))) unsigned int*)l, 16, 0, 0);
}

// ---------------- CSR build ----------------
__global__ void k_deg(const int* __restrict__ ei, int E, int Np, int* __restrict__ deg) {
    int e = blockIdx.x * blockDim.x + threadIdx.x;
    if (e >= E + Np) return;
    int dst = (e < E) ? ei[E + e] : (e - E);
    atomicAdd(&deg[dst], 1);
}

__global__ LB(512) void k_scan(const int* __restrict__ deg, int* __restrict__ row_ptr,
                               int* __restrict__ cursor, int n) {
    __shared__ int sh[512];
    __shared__ int carry_sh;
    int t = threadIdx.x;
    if (t == 0) { carry_sh = 0; row_ptr[0] = 0; }
    __syncthreads();
    for (int base = 0; base < n; base += 512) {
        int i = base + t;
        int v = (i < n) ? deg[i] : 0;
        sh[t] = v;
        __syncthreads();
        for (int off = 1; off < 512; off <<= 1) {
            int add = (t >= off) ? sh[t - off] : 0;
            __syncthreads();
            sh[t] += add;
            __syncthreads();
        }
        int carry = carry_sh;
        if (i < n) {
            int inc = sh[t] + carry;
            row_ptr[i + 1] = inc;
            cursor[i] = inc - v;
        }
        __syncthreads();
        if (t == 511) carry_sh = carry + sh[511];
        __syncthreads();
    }
}

__global__ void k_fill(const int* __restrict__ ei, int E, int Np,
                       int* __restrict__ cursor, int* __restrict__ col_src) {
    int e = blockIdx.x * blockDim.x + threadIdx.x;
    if (e >= E + Np) return;
    int src, dst;
    if (e < E) { src = ei[e]; dst = ei[E + e]; }
    else       { src = dst = e - E; }
    int pos = atomicAdd(&cursor[dst], 1);
    col_src[pos] = src;
}

// ---------------- fp32 -> hi/lo planes ----------------
__global__ void k_pack(const float* __restrict__ in, u16* __restrict__ hi,
                       u16* __restrict__ lo, int n4) {
    int i = blockIdx.x * blockDim.x + threadIdx.x;
    if (i >= n4) return;
    float4 v = ((const float4*)in)[i];
    ushort4 h, l;
    h.x = f2b(v.x); l.x = f2b(v.x - b2f(h.x));
    h.y = f2b(v.y); l.y = f2b(v.y - b2f(h.y));
    h.z = f2b(v.z); l.z = f2b(v.z - b2f(h.z));
    h.w = f2b(v.w); l.w = f2b(v.w - b2f(h.w));
    ((ushort4*)hi)[i] = h;
    ((ushort4*)lo)[i] = l;
}

// ---------------- weight transpose + split: Wt[n][k] planes ----------------
__global__ LB(256) void k_wt_pack(const float* __restrict__ W, u16* __restrict__ Whi,
                                  u16* __restrict__ Wlo, int K, int Nn) {
    __shared__ float sh[32][33];
    int n0 = blockIdx.x * 32, k0 = blockIdx.y * 32;
    int c = threadIdx.x & 31, r0 = threadIdx.x >> 5;
    #pragma unroll
    for (int r = r0; r < 32; r += 8)
        sh[r][c] = W[(size_t)(k0 + r) * Nn + n0 + c];
    __syncthreads();
    #pragma unroll
    for (int r = r0; r < 32; r += 8) {
        float v = sh[c][r];
        u16 hi = f2b(v);
        Whi[(size_t)(n0 + r) * K + k0 + c] = hi;
        Wlo[(size_t)(n0 + r) * K + k0 + c] = f2b(v - b2f(hi));
    }
}

// ---------------- split-plane MFMA GEMM: C = A[M,K] @ Bt[Nn,K]^T -----------
// 128x128 tile, BK=32, 4 waves (2x2), 64x64/wave, 48 MFMA/K-step/wave.
// LDS tiles XOR-swizzled: data (r,kc16B) at byte (r*64+kc*16)^((r&7)<<4);
// global_load_lds source is inverse-permuted so linear LDS dest works.
__global__ LB(256) void k_gemm_pl(const u16* __restrict__ Ahi, const u16* __restrict__ Alo,
                                  const u16* __restrict__ Bhi, const u16* __restrict__ Blo,
                                  const float* __restrict__ bias,
                                  u16* __restrict__ Chi, u16* __restrict__ Clo,
                                  int M, int K, int Nn) {
    __shared__ u16 AsHi[128 * 32], AsLo[128 * 32], BsHi[128 * 32], BsLo[128 * 32];
    const int tid  = threadIdx.x;
    const int lane = tid & 63;
    const int w    = tid >> 6;
    const int wr   = w >> 1;
    const int wc   = w & 1;
    const int row0 = blockIdx.y * 128;
    const int col0 = blockIdx.x * 128;
    const int ln15 = lane & 15;
    const int lq   = lane >> 4;

    f32x4 acc[4][4];
    #pragma unroll
    for (int m = 0; m < 4; ++m)
        #pragma unroll
        for (int n = 0; n < 4; ++n) acc[m][n] = (f32x4){0.f, 0.f, 0.f, 0.f};

    for (int k0 = 0; k0 < K; k0 += 32) {
        // stage: 512 16B-chunks per tile, 2 per thread per tile.
        #pragma unroll
        for (int i = 0; i < 2; ++i) {
            int c = i * 256 + tid;
            // inverse of swizzle: slot c holds element (r, kc)
            int r  = 2 * (c >> 3) + (((c >> 2) ^ (c >> 4)) & 1);
            int kc = (c & 3) ^ (r & 3);
            int gra = row0 + r; if (gra >= M) gra = M - 1;   // tail clamp
            size_t ga = (size_t)gra * K + k0 + kc * 8;
            size_t gb = (size_t)(col0 + r) * K + k0 + kc * 8;
            lds_cp16(Ahi + ga, (char*)AsHi + c * 16);
            lds_cp16(Alo + ga, (char*)AsLo + c * 16);
            lds_cp16(Bhi + gb, (char*)BsHi + c * 16);
            lds_cp16(Blo + gb, (char*)BsLo + c * 16);
        }
        __syncthreads();
        bf16x8 ah[4], al[4], bh[4], bl[4];
        #pragma unroll
        for (int m = 0; m < 4; ++m) {
            int row = wr * 64 + m * 16 + ln15;
            int byo = (row * 64 + lq * 16) ^ ((row & 7) << 4);
            ah[m] = *(const bf16x8*)((const char*)AsHi + byo);
            al[m] = *(const bf16x8*)((const char*)AsLo + byo);
        }
        #pragma unroll
        for (int n = 0; n < 4; ++n) {
            int row = wc * 64 + n * 16 + ln15;
            int byo = (row * 64 + lq * 16) ^ ((row & 7) << 4);
            bh[n] = *(const bf16x8*)((const char*)BsHi + byo);
            bl[n] = *(const bf16x8*)((const char*)BsLo + byo);
        }
        #pragma unroll
        for (int m = 0; m < 4; ++m)
            #pragma unroll
            for (int n = 0; n < 4; ++n) {
                acc[m][n] = __builtin_amdgcn_mfma_f32_16x16x32_bf16(al[m], bh[n], acc[m][n], 0, 0, 0);
                acc[m][n] = __builtin_amdgcn_mfma_f32_16x16x32_bf16(ah[m], bl[n], acc[m][n], 0, 0, 0);
                acc[m][n] = __builtin_amdgcn_mfma_f32_16x16x32_bf16(ah[m], bh[n], acc[m][n], 0, 0, 0);
            }
        __syncthreads();
    }

    // D: col = lane&15, row = (lane>>4)*4 + j  [m89/m91-verified]
    #pragma unroll
    for (int m = 0; m < 4; ++m) {
        #pragma unroll
        for (int n = 0; n < 4; ++n) {
            int gc = col0 + wc * 64 + n * 16 + ln15;
            float badd = bias ? bias[gc] : 0.f;
            #pragma unroll
            for (int j = 0; j < 4; ++j) {
                int gr = row0 + wr * 64 + m * 16 + lq * 4 + j;
                if (gr < M) {
                    float v = acc[m][n][j] + badd;
                    u16 hi = f2b(v);
                    size_t o = (size_t)gr * Nn + gc;
                    Chi[o] = hi;
                    Clo[o] = f2b(v - b2f(hi));
                }
            }
        }
    }
}

// ---------------- attention scalars from hi/lo planes ----------------
// grid = N, block = 64*H; C == 512.
__global__ void k_att(const u16* __restrict__ Hhi, const u16* __restrict__ Hlo,
                      const float* __restrict__ att_s, const float* __restrict__ att_d,
                      float* __restrict__ a_src, float* __restrict__ a_dst,
                      int H, int C) {
    int n = blockIdx.x;
    int w = threadIdx.x >> 6;
    int lane = threadIdx.x & 63;
    size_t o = (size_t)n * H * C + (size_t)w * C + lane * 8;
    bf16x8 vh = *(const bf16x8*)(Hhi + o);
    bf16x8 vl = *(const bf16x8*)(Hlo + o);
    float s1 = 0.f, s2 = 0.f;
    int ob = w * C + lane * 8;
    #pragma unroll
    for (int j = 0; j < 8; ++j) {
        float hv = b2f((u16)vh[j]) + b2f((u16)vl[j]);
        s1 = fmaf(hv, att_s[ob + j], s1);
        s2 = fmaf(hv, att_d[ob + j], s2);
    }
    #pragma unroll
    for (int off = 32; off; off >>= 1) {
        s1 += __shfl_xor(s1, off);
        s2 += __shfl_xor(s2, off);
    }
    if (lane == 0) { a_src[n * H + w] = s1; a_dst[n * H + w] = s2; }
}

// ---------------- segment softmax per dst (one wave) ----------------
__global__ LB(64) void k_softmax(const int* __restrict__ row_ptr, const int* __restrict__ col_src,
                                 const float* __restrict__ a_src, const float* __restrict__ a_dst,
                                 float* __restrict__ alpha, int H) {
    int d = blockIdx.x;
    int t = threadIdx.x;
    int s = row_ptr[d], eend = row_ptr[d + 1];
    for (int h = 0; h < H; ++h) {
        float adh = a_dst[d * H + h];
        float m = -1e30f;
        for (int e = s + t; e < eend; e += 64) {
            float v = a_src[col_src[e] * H + h] + adh;
            v = (v > 0.f) ? v : 0.2f * v;
            m = fmaxf(m, v);
        }
        #pragma unroll
        for (int off = 32; off; off >>= 1) m = fmaxf(m, __shfl_xor(m, off));
        float sum = 0.f;
        for (int e = s + t; e < eend; e += 64) {
            float v = a_src[col_src[e] * H + h] + adh;
            v = (v > 0.f) ? v : 0.2f * v;
            sum += __expf(v - m);
        }
        #pragma unroll
        for (int off = 32; off; off >>= 1) sum += __shfl_xor(sum, off);
        float inv = 1.0f / sum;
        for (int e = s + t; e < eend; e += 64) {
            float v = a_src[col_src[e] * H + h] + adh;
            v = (v > 0.f) ? v : 0.2f * v;
            alpha[e * H + h] = __expf(v - m) * inv;
        }
    }
}

// ---------------- aggregate: out[d] = sum_e alpha[e,h]*h[src] (+bias,ELU) --
// block = F/8 threads; each thread owns 8 contiguous elements.
template <bool PLANES_OUT, bool ELU_>
__global__ LB(256) void k_agg(const int* __restrict__ row_ptr, const int* __restrict__ col_src,
                              const float* __restrict__ alpha,
                              const u16* __restrict__ Hhi, const u16* __restrict__ Hlo,
                              const float* __restrict__ bias,
                              u16* __restrict__ Ohi, u16* __restrict__ Olo,
                              float* __restrict__ Of, int H, int C) {
    int d = blockIdx.x;
    int tid = threadIdx.x;
    int F = H * C;
    int o = tid * 8;
    int h0 = o / C;   // wave-uniform for C=512
    float acc[8];
    #pragma unroll
    for (int j = 0; j < 8; ++j) acc[j] = 0.f;
    int s = row_ptr[d], eend = row_ptr[d + 1];
    for (int e = s; e < eend; ++e) {
        int src = col_src[e];
        float a = alpha[e * H + h0];
        size_t go = (size_t)src * F + o;
        bf16x8 vh = *(const bf16x8*)(Hhi + go);
        bf16x8 vl = *(const bf16x8*)(Hlo + go);
        #pragma unroll
        for (int j = 0; j < 8; ++j)
            acc[j] = fmaf(a, b2f((u16)vh[j]) + b2f((u16)vl[j]), acc[j]);
    }
    #pragma unroll
    for (int j = 0; j < 8; ++j) {
        acc[j] += bias[o + j];
        if (ELU_) acc[j] = (acc[j] > 0.f) ? acc[j] : __expf(acc[j]) - 1.f;
    }
    if (PLANES_OUT) {
        bf16x8 rh, rl;
        #pragma unroll
        for (int j = 0; j < 8; ++j) {
            u16 hi = f2b(acc[j]);
            rh[j] = (short)hi;
            rl[j] = (short)f2b(acc[j] - b2f(hi));
        }
        *(bf16x8*)(Ohi + (size_t)d * F + o) = rh;
        *(bf16x8*)(Olo + (size_t)d * F + o) = rl;
    } else {
        float* po = Of + (size_t)d * F + o;
        #pragma unroll
        for (int j4 = 0; j4 < 2; ++j4) {
            float4 r;
            r.x = acc[j4 * 4 + 0]; r.y = acc[j4 * 4 + 1];
            r.z = acc[j4 * 4 + 2]; r.w = acc[j4 * 4 + 3];
            *(float4*)&po[j4 * 4] = r;
        }
    }
}

// ---------------------------------------------------------------------------
extern "C" void kernel_launch(void* const* d_in, const int* in_sizes, int n_in,
                              void* d_out, int out_size, void* d_ws, size_t ws_size,
                              hipStream_t stream) {
    const float* x      = (const float*)d_in[0];
    const int*   ei     = (const int*)d_in[1];
    const float* proj_W = (const float*)d_in[2];
    const float* proj_b = (const float*)d_in[3];
    const float* W1  = (const float*)d_in[4];
    const float* as1 = (const float*)d_in[5];
    const float* ad1 = (const float*)d_in[6];
    const float* b1  = (const float*)d_in[7];
    const float* W2  = (const float*)d_in[8];
    const float* as2 = (const float*)d_in[9];
    const float* ad2 = (const float*)d_in[10];
    const float* b2  = (const float*)d_in[11];
    const float* W3  = (const float*)d_in[12];
    const float* as3 = (const float*)d_in[13];
    const float* ad3 = (const float*)d_in[14];
    const float* b3  = (const float*)d_in[15];

    const int N  = in_sizes[0] / 256;   // 10000
    const int E  = in_sizes[1] / 2;     // 160000
    const int Ep = E + N;

    size_t off = 0;
    auto alloc = [&](size_t bytes) -> void* {
        void* p = (char*)d_ws + off;
        off += (bytes + 255) & ~(size_t)255;
        return p;
    };
    u16* bufA_hi = (u16*)alloc((size_t)N * 2048 * 2);
    u16* bufA_lo = (u16*)alloc((size_t)N * 2048 * 2);
    u16* bufB_hi = (u16*)alloc((size_t)N * 2048 * 2);
    u16* bufB_lo = (u16*)alloc((size_t)N * 2048 * 2);
    float* a_src   = (float*)alloc((size_t)N * 4 * 4);
    float* a_dst   = (float*)alloc((size_t)N * 4 * 4);
    float* alpha   = (float*)alloc((size_t)Ep * 4 * 4);
    int*   deg     = (int*)alloc((size_t)N * 4);
    int*   cursor  = (int*)alloc((size_t)N * 4);
    int*   row_ptr = (int*)alloc((size_t)(N + 1) * 4);
    int*   col_src = (int*)alloc((size_t)Ep * 4);
    (void)ws_size;

    // JIT weight planes live in d_out (2*8.39 MB = 16.78 MB <= 20.48 MB);
    // consumed by GEMMs, then fully overwritten by the final aggregate.
    u16* whi = (u16*)d_out;
    u16* wlo = (u16*)d_out + (size_t)2048 * 2048;

    // ---- CSR build ----
    hipMemsetAsync(deg, 0, (size_t)N * 4, stream);
    int eb = (Ep + 255) / 256;
    k_deg<<<eb, 256, 0, stream>>>(ei, E, N, deg);
    k_scan<<<1, 512, 0, stream>>>(deg, row_ptr, cursor, N);
    k_fill<<<eb, 256, 0, stream>>>(ei, E, N, cursor, col_src);

    const int MB = (N + 127) / 128;  // 79

    // ---- pack x into bufB planes [N,256] ----
    k_pack<<<(N * 256 / 4 + 255) / 256, 256, 0, stream>>>(x, bufB_hi, bufB_lo, N * 256 / 4);

    // ---- proj: bufA = x @ proj_W + proj_b  [N,512] ----
    k_wt_pack<<<dim3(512 / 32, 256 / 32), 256, 0, stream>>>(proj_W, whi, wlo, 256, 512);
    k_gemm_pl<<<dim3(512 / 128, MB), 256, 0, stream>>>(bufB_hi, bufB_lo, whi, wlo, proj_b,
                                                       bufA_hi, bufA_lo, N, 256, 512);

    // ---- layer 1 (H=4, C=512, concat, ELU) ----
    k_wt_pack<<<dim3(2048 / 32, 512 / 32), 256, 0, stream>>>(W1, whi, wlo, 512, 2048);
    k_gemm_pl<<<dim3(2048 / 128, MB), 256, 0, stream>>>(bufA_hi, bufA_lo, whi, wlo, nullptr,
                                                        bufB_hi, bufB_lo, N, 512, 2048);
    k_att<<<N, 256, 0, stream>>>(bufB_hi, bufB_lo, as1, ad1, a_src, a_dst, 4, 512);
    k_softmax<<<N, 64, 0, stream>>>(row_ptr, col_src, a_src, a_dst, alpha, 4);
    k_agg<true, true><<<N, 256, 0, stream>>>(row_ptr, col_src, alpha, bufB_hi, bufB_lo,
                                             b1, bufA_hi, bufA_lo, nullptr, 4, 512);

    // ---- layer 2 (H=4, C=512, concat, ELU) ----
    k_wt_pack<<<dim3(2048 / 32, 2048 / 32), 256, 0, stream>>>(W2, whi, wlo, 2048, 2048);
    k_gemm_pl<<<dim3(2048 / 128, MB), 256, 0, stream>>>(bufA_hi, bufA_lo, whi, wlo, nullptr,
                                                        bufB_hi, bufB_lo, N, 2048, 2048);
    k_att<<<N, 256, 0, stream>>>(bufB_hi, bufB_lo, as2, ad2, a_src, a_dst, 4, 512);
    k_softmax<<<N, 64, 0, stream>>>(row_ptr, col_src, a_src, a_dst, alpha, 4);
    k_agg<true, true><<<N, 256, 0, stream>>>(row_ptr, col_src, alpha, bufB_hi, bufB_lo,
                                             b2, bufA_hi, bufA_lo, nullptr, 4, 512);

    // ---- layer 3 (H=1, C=512, mean over single head = identity, no ELU) ----
    k_wt_pack<<<dim3(512 / 32, 2048 / 32), 256, 0, stream>>>(W3, whi, wlo, 2048, 512);
    k_gemm_pl<<<dim3(512 / 128, MB), 256, 0, stream>>>(bufA_hi, bufA_lo, whi, wlo, nullptr,
                                                       bufB_hi, bufB_lo, N, 2048, 512);
    k_att<<<N, 64, 0, stream>>>(bufB_hi, bufB_lo, as3, ad3, a_src, a_dst, 1, 512);
    k_softmax<<<N, 64, 0, stream>>>(row_ptr, col_src, a_src, a_dst, alpha, 1);
    k_agg<false, false><<<N, 64, 0, stream>>>(row_ptr, col_src, alpha, bufB_hi, bufB_lo,
                                              b3, nullptr, nullptr, (float*)d_out, 1, 512);
}